// Round 6
// baseline (976.027 us; speedup 1.0000x reference)
//
#include <hip/hip_runtime.h>
#include <hip/hip_bf16.h>

#define VOCAB 100
#define EDIM  128
#define HDIM  256
#define LDIM  64
#define G3    768
#define TT    128
#define BB    4096
#define LROW  (TT * VOCAB)
#define H_LD  264            // halfs per h-row: 256 + 8 pad -> row stride 528B = 16 mod 128
#define ZP_LD 17             // f16x4 units per zp col (16 rows + 1 pad) -> 136B stride

typedef float    f32x4 __attribute__((ext_vector_type(4)));
typedef _Float16 f16x8 __attribute__((ext_vector_type(8)));
typedef _Float16 f16x4 __attribute__((ext_vector_type(4)));

__device__ __forceinline__ float sigf(float x) {
    return __builtin_amdgcn_rcpf(1.0f + __expf(-x));
}
__device__ __forceinline__ float tanh_f(float x) {
    return 2.0f * __builtin_amdgcn_rcpf(1.0f + __expf(-2.0f * x)) - 1.0f;
}

// LDS-only barrier: waits ds ops (lgkmcnt) but leaves global stores/loads in
// flight across steps (avoids the __syncthreads vmcnt(0) store-drain).
__device__ __forceinline__ void barrier_lgkm() {
    asm volatile("s_waitcnt lgkmcnt(0)\n\ts_barrier" ::: "memory");
}

// B fragment, linear K: lane(l15=col, lgrp) elem e holds B[k=ks*32+lgrp*8+e][outcol]
__device__ __forceinline__ f16x8 ld_bfrag(const float* __restrict__ W, int outcol, int ks, int lgrp) {
    const float* p = W + outcol * HDIM + ks * 32 + lgrp * 8;
    float4 a = *(const float4*)p;
    float4 b = *(const float4*)(p + 4);
    f16x8 w = {(_Float16)a.x, (_Float16)a.y, (_Float16)a.z, (_Float16)a.w,
               (_Float16)b.x, (_Float16)b.y, (_Float16)b.z, (_Float16)b.w};
    return w;
}

// ---------------- prep: PT2[v][g] = enc_Wih@emb[v] + enc_bih + (g<512 ? enc_bhh : 0), f16 ----------------
__global__ void pt_kernel(const float* __restrict__ emb, const float* __restrict__ Wih,
                          const float* __restrict__ bih, const float* __restrict__ bhh,
                          _Float16* __restrict__ PT) {
    int v = blockIdx.x;
    __shared__ float se[EDIM];
    for (int e = threadIdx.x; e < EDIM; e += blockDim.x) se[e] = emb[v * EDIM + e];
    __syncthreads();
    for (int g = threadIdx.x; g < G3; g += blockDim.x) {
        const float* wr = Wih + g * EDIM;
        float acc = bih[g] + (g < 512 ? bhh[g] : 0.0f);
        #pragma unroll 8
        for (int e = 0; e < EDIM; ++e) acc += se[e] * wr[e];
        PT[v * G3 + g] = (_Float16)acc;
    }
}

// ===================================================================
// ENCODER: 1024 thr / 16 waves; wave wv owns output cols wv*16..+16 for
// all 3 gates (96 weight VGPRs). h_prev lives in lane registers (f32).
// ===================================================================
__global__ __launch_bounds__(1024, 4) void enc_kernel(
    const int* __restrict__ x, const _Float16* __restrict__ PT2,
    const float* __restrict__ Whh, const float* __restrict__ bhh,
    float* __restrict__ out)
{
    __shared__ _Float16 s_h[2][16 * H_LD];   // 2 x 8448 B
    __shared__ int s_tok[16 * TT];           // 8192 B

    const int tid  = threadIdx.x;
    const int lane = tid & 63;
    const int wv   = tid >> 6;               // 0..15
    const int l15  = lane & 15;
    const int lgrp = lane >> 4;
    const int bbase = blockIdx.x * 16;
    const int col  = wv * 16 + l15;          // this lane's output/gate column

    for (int i = tid; i < 16 * TT; i += 1024) s_tok[i] = x[bbase * TT + i];

    f16x8 Breg[3][8];
    #pragma unroll
    for (int g = 0; g < 3; ++g)
        #pragma unroll
        for (int ks = 0; ks < 8; ++ks)
            Breg[g][ks] = ld_bfrag(Whh, g * 256 + col, ks, lgrp);

    const float bhn = bhh[512 + col];
    float hst[4] = {0.f, 0.f, 0.f, 0.f};

    for (int i = tid; i < 16 * H_LD; i += 1024) s_h[0][i] = (_Float16)0.f;
    __syncthreads();

    const f32x4 z4 = {0.f, 0.f, 0.f, 0.f};

    #pragma unroll 1
    for (int t = 0; t < TT; ++t) {
        const _Float16* rh = s_h[t & 1];
        _Float16* wh = s_h[(t + 1) & 1];

        f32x4 a0 = z4, a1 = z4, a2 = z4;
        #pragma unroll
        for (int ks = 0; ks < 8; ++ks) {
            f16x8 a = *(const f16x8*)(rh + l15 * H_LD + ks * 32 + lgrp * 8);
            a0 = __builtin_amdgcn_mfma_f32_16x16x32_f16(a, Breg[0][ks], a0, 0, 0, 0);
            a1 = __builtin_amdgcn_mfma_f32_16x16x32_f16(a, Breg[1][ks], a1, 0, 0, 0);
            a2 = __builtin_amdgcn_mfma_f32_16x16x32_f16(a, Breg[2][ks], a2, 0, 0, 0);
        }
        #pragma unroll
        for (int j = 0; j < 4; ++j) {
            const int row = lgrp * 4 + j;
            const int tok = s_tok[row * TT + t];
            const _Float16* p = PT2 + tok * G3 + col;
            float xr = (float)p[0], xz = (float)p[256], xn = (float)p[512];
            float rg = sigf(a0[j] + xr);
            float zg = sigf(a1[j] + xz);
            float n  = tanh_f(xn + rg * (a2[j] + bhn));
            float h  = n + zg * (hst[j] - n);
            hst[j] = h;
            wh[row * H_LD + col] = (_Float16)h;
            if (t == TT - 1) out[(size_t)(bbase + row) * LROW + col] = h;
        }
        barrier_lgkm();
    }
}

// ===================================================================
// DECODER: 1024 thr / 16 waves; prologue (mu/lv/z/proj) + GRU loop with
// fused vocab projection (waves 0..6). Per-step barrier is LDS-only so
// logits stores stream across steps.
// ===================================================================
__global__ __launch_bounds__(1024, 4) void dec_kernel(
    const float* __restrict__ eps,
    const float* __restrict__ mu_W, const float* __restrict__ mu_b,
    const float* __restrict__ lv_W, const float* __restrict__ lv_b,
    const float* __restrict__ di_W, const float* __restrict__ di_b,
    const float* __restrict__ dec_Wih, const float* __restrict__ dec_Whh,
    const float* __restrict__ dec_bih, const float* __restrict__ dec_bhh,
    const float* __restrict__ out_W, const float* __restrict__ out_b,
    float* __restrict__ out)
{
    __shared__ _Float16 s_hb[2][16 * H_LD];                                 // 16896 B
    __shared__ f16x4 s_zp[256 * ZP_LD];                                     // 34816 B {r,z,n,_}
    __shared__ __attribute__((aligned(16))) unsigned char s_outw[VOCAB * 512]; // 51200 B f16 swizzled
    __shared__ float s_hl[16 * 260];                                        // 16640 B

    const int tid  = threadIdx.x;
    const int lane = tid & 63;
    const int wv   = tid >> 6;
    const int l15  = lane & 15;
    const int lgrp = lane >> 4;
    const int bbase = blockIdx.x * 16;
    const int col  = wv * 16 + l15;

    // h_last stash -> LDS; stage out_W (f16, XOR-swizzled)
    for (int i = tid; i < 16 * HDIM; i += 1024) {
        int m = i >> 8, c = i & 255;
        s_hl[m * 260 + c] = out[(size_t)(bbase + m) * LROW + c];
    }
    for (int idx = tid; idx < VOCAB * HDIM; idx += 1024) {
        int r = idx >> 8, k = idx & 255;
        _Float16 w = (_Float16)out_W[r * 256 + k];
        *(short*)(s_outw + r * 512 + ((2 * k) ^ ((r & 7) << 4))) = __builtin_bit_cast(short, w);
    }

    f16x8 Breg[3][8];
    #pragma unroll
    for (int g = 0; g < 3; ++g)
        #pragma unroll
        for (int ks = 0; ks < 8; ++ks)
            Breg[g][ks] = ld_bfrag(dec_Whh, g * 256 + col, ks, lgrp);
    __syncthreads();

    // ---- mu / logvar / z : one (m,j) per thread ----
    float zv;
    {
        const size_t MU_OFF = (size_t)BB * TT * VOCAB;
        const size_t LV_OFF = MU_OFF + (size_t)BB * LDIM;
        int m = tid >> 6, j = tid & 63;
        const float* mwr = mu_W + j * HDIM;
        const float* lwr = lv_W + j * HDIM;
        float am = mu_b[j], al = lv_b[j];
        #pragma unroll 4
        for (int k = 0; k < HDIM; ++k) { float hv = s_hl[m * 260 + k]; am += hv * mwr[k]; al += hv * lwr[k]; }
        size_t bo = (size_t)(bbase + m) * LDIM + j;
        out[MU_OFF + bo] = am;
        out[LV_OFF + bo] = al;
        zv = am + eps[bo] * __expf(0.5f * al);
    }
    __syncthreads();                     // all h_last reads done
    { int m = tid >> 6, j = tid & 63; s_hl[m * 260 + j] = zv; }
    __syncthreads();                     // z staged (cols 0..63)

    // ---- hidden = tanh(di_W z + di_b); zp = dec_Wih z + dec_bih (+bhh r,z) ----
    float th[4];
    {
        const int gc = tid & 255;
        const int gm = tid >> 8;         // 0..3 -> rows gm*4..+4
        float ah[4], ar[4], az[4], an[4];
        float dib = di_b[gc];
        float bir = dec_bih[gc], biz = dec_bih[gc + 256], bin_ = dec_bih[gc + 512];
        #pragma unroll
        for (int i = 0; i < 4; ++i) { ah[i] = dib; ar[i] = bir; az[i] = biz; an[i] = bin_; }
        const float* w0 = di_W + gc * LDIM;
        const float* w1 = dec_Wih + gc * LDIM;
        const float* w2 = dec_Wih + (gc + 256) * LDIM;
        const float* w3 = dec_Wih + (gc + 512) * LDIM;
        #pragma unroll 2
        for (int j = 0; j < LDIM; ++j) {
            float a0 = w0[j], a1 = w1[j], a2 = w2[j], a3 = w3[j];
            #pragma unroll
            for (int i = 0; i < 4; ++i) {
                float q = s_hl[(gm * 4 + i) * 260 + j];
                ah[i] += q * a0; ar[i] += q * a1; az[i] += q * a2; an[i] += q * a3;
            }
        }
        float bhr = dec_bhh[gc], bhz = dec_bhh[gc + 256];
        __syncthreads();                 // all z reads done before s_hl overwrite
        #pragma unroll
        for (int i = 0; i < 4; ++i) {
            int r = gm * 4 + i;
            th[i] = tanh_f(ah[i]);
            s_hl[r * 260 + gc] = th[i];
            f16x4 q = {(_Float16)(ar[i] + bhr), (_Float16)(az[i] + bhz), (_Float16)an[i], (_Float16)0.f};
            s_zp[gc * ZP_LD + r] = q;
            s_hb[0][r * H_LD + gc] = (_Float16)th[i];
        }
    }
    __syncthreads();                     // th/zp/h0 staged

    float hpr[4];
    #pragma unroll
    for (int j = 0; j < 4; ++j) hpr[j] = s_hl[(lgrp * 4 + j) * 260 + col];

    const float bhn = dec_bhh[512 + col];
    const int vcol = wv * 16 + l15;
    const int orow = (vcol < VOCAB) ? vcol : (VOCAB - 1);
    const float ob = (wv < 7 && vcol < VOCAB) ? out_b[vcol] : 0.0f;
    const f32x4 z4 = {0.f, 0.f, 0.f, 0.f};

    #pragma unroll 1
    for (int t = 0; t < TT; ++t) {
        const _Float16* rh = s_hb[t & 1];
        _Float16* wh = s_hb[(t + 1) & 1];

        f32x4 a0 = z4, a1 = z4, a2 = z4, aco = z4;
        #pragma unroll
        for (int ks = 0; ks < 8; ++ks) {
            f16x8 a = *(const f16x8*)(rh + l15 * H_LD + ks * 32 + lgrp * 8);
            a0 = __builtin_amdgcn_mfma_f32_16x16x32_f16(a, Breg[0][ks], a0, 0, 0, 0);
            a1 = __builtin_amdgcn_mfma_f32_16x16x32_f16(a, Breg[1][ks], a1, 0, 0, 0);
            a2 = __builtin_amdgcn_mfma_f32_16x16x32_f16(a, Breg[2][ks], a2, 0, 0, 0);
            if (wv < 7) {
                f16x8 wo = *(const f16x8*)(s_outw + orow * 512 + ((ks * 64 + lgrp * 16) ^ ((orow & 7) << 4)));
                aco = __builtin_amdgcn_mfma_f32_16x16x32_f16(a, wo, aco, 0, 0, 0);
            }
        }

        if (t > 0 && wv < 7 && vcol < VOCAB) {   // logits[:, t-1, :] from h_t
            size_t base = (size_t)(bbase + lgrp * 4) * LROW + (size_t)(t - 1) * VOCAB + vcol;
            #pragma unroll
            for (int j = 0; j < 4; ++j) out[base + (size_t)j * LROW] = aco[j] + ob;
        }

        #pragma unroll
        for (int j = 0; j < 4; ++j) {
            const int row = lgrp * 4 + j;
            f16x4 q = s_zp[col * ZP_LD + lgrp * 4 + j];
            float rg = sigf(a0[j] + (float)q[0]);
            float zg = sigf(a1[j] + (float)q[1]);
            float n  = tanh_f((float)q[2] + rg * (a2[j] + bhn));
            float h  = n + zg * (hpr[j] - n);
            hpr[j] = h;
            wh[row * H_LD + col] = (_Float16)h;
        }
        barrier_lgkm();
    }

    // logits[:, 127, :] from h_128 (buf 0, TT even)
    if (wv < 7) {
        const _Float16* rh = s_hb[0];
        f32x4 aco = z4;
        #pragma unroll
        for (int ks = 0; ks < 8; ++ks) {
            f16x8 a  = *(const f16x8*)(rh + l15 * H_LD + ks * 32 + lgrp * 8);
            f16x8 wo = *(const f16x8*)(s_outw + orow * 512 + ((ks * 64 + lgrp * 16) ^ ((orow & 7) << 4)));
            aco = __builtin_amdgcn_mfma_f32_16x16x32_f16(a, wo, aco, 0, 0, 0);
        }
        if (vcol < VOCAB) {
            size_t base = (size_t)(bbase + lgrp * 4) * LROW + (size_t)(TT - 1) * VOCAB + vcol;
            #pragma unroll
            for (int j = 0; j < 4; ++j) out[base + (size_t)j * LROW] = aco[j] + ob;
        }
    }
}

extern "C" void kernel_launch(void* const* d_in, const int* in_sizes, int n_in,
                              void* d_out, int out_size, void* d_ws, size_t ws_size,
                              hipStream_t stream) {
    const int*   x       = (const int*)  d_in[0];
    const float* eps     = (const float*)d_in[1];
    const float* emb     = (const float*)d_in[2];
    const float* enc_Wih = (const float*)d_in[3];
    const float* enc_Whh = (const float*)d_in[4];
    const float* enc_bih = (const float*)d_in[5];
    const float* enc_bhh = (const float*)d_in[6];
    const float* mu_W    = (const float*)d_in[7];
    const float* mu_b    = (const float*)d_in[8];
    const float* lv_W    = (const float*)d_in[9];
    const float* lv_b    = (const float*)d_in[10];
    const float* di_W    = (const float*)d_in[11];
    const float* di_b    = (const float*)d_in[12];
    const float* dec_Wih = (const float*)d_in[13];
    const float* dec_Whh = (const float*)d_in[14];
    const float* dec_bih = (const float*)d_in[15];
    const float* dec_bhh = (const float*)d_in[16];
    const float* out_W   = (const float*)d_in[17];
    const float* out_b   = (const float*)d_in[18];
    float* out = (float*)d_out;
    _Float16* PT = (_Float16*)d_ws;   // [100][768] f16 = 153600 B

    pt_kernel<<<VOCAB, 256, 0, stream>>>(emb, enc_Wih, enc_bih, enc_bhh, PT);
    enc_kernel<<<BB / 16, 1024, 0, stream>>>(x, PT, enc_Whh, enc_bhh, out);
    dec_kernel<<<BB / 16, 1024, 0, stream>>>(eps, mu_W, mu_b, lv_W, lv_b,
        di_W, di_b, dec_Wih, dec_Whh, dec_bih, dec_bhh, out_W, out_b, out);
}